// Round 2
// baseline (184.083 us; speedup 1.0000x reference)
//
#include <hip/hip_runtime.h>
#include <hip/hip_bf16.h>
#include <math.h>

// Problem constants (fixed by setup_inputs)
#define BB 4
#define NN 48
#define SS 32
#define AA 16
#define AI 8
#define EE 512
#define KK 16
#define NBLK (BB * EE)   // 2048 edge blocks
#define NNODE (BB * NN)  // 192 nodes

// ws layout (byte offsets)
#define WS_CNT 0               // 1 int arrival counter
#define WS_NG  256             // NNODE floats (node gold)
#define WS_EG  1280            // NBLK floats (edge gold)

__device__ __forceinline__ bool read_mask(const void* p, int idx, int flag) {
    if (flag == 1) return ((const unsigned char*)p)[idx] != 0;
    if (flag == 2) return ((const float*)p)[idx] != 0.0f;
    return ((const int*)p)[idx] != 0;
}

// Per-wave node routine: weighted unaries for all 32 states, stable top-16
// rank select (target forced to rank 0 via +inf key), optional beam write to
// LDS and optional unary-gold write to global.
__device__ __forceinline__ void node_beam(
    int node, int lane, int flag,
    const float* __restrict__ unaries, const float* __restrict__ behaviors,
    const void* masks, const int* __restrict__ targets,
    const float* __restrict__ wpu, const void* bmask,
    int* beam16, float* gold_out)
{
    float m = read_mask(masks, node, flag) ? 1.f : 0.f;
    int tgt = targets[node];

    float val = -INFINITY, key = -INFINITY;
    if (lane < SS) {
        int s = lane;
        float u = unaries[node * SS + s];
        const float* bp = behaviors + ((size_t)node * SS + s) * AA;
        float cnt = 0.f, raw = 0.f;
        #pragma unroll
        for (int a = 0; a < AA; ++a) {
            bool mm = read_mask(bmask, s * AA + a, flag);
            cnt += mm ? 1.f : 0.f;
            raw += mm ? bp[a] : 0.f;
        }
        if (cnt == 0.f) cnt = 1.f;
        val = m * (u + wpu[s] * (raw / cnt));   // weighted_unaries
        key = (s == tgt) ? INFINITY : val;      // _u with target -> +inf
    }

    // rank = #states with strictly greater key, ties broken by lower index
    int rank = 0;
    #pragma unroll
    for (int t = 0; t < SS; ++t) {
        float kt = __shfl(key, t, 64);
        rank += (kt > key) || (kt == key && t < lane);
    }
    bool sel = (lane < SS) && (rank < KK);
    if (beam16 && sel) beam16[rank] = lane;

    if (gold_out) {
        float mv = sel ? val : -INFINITY;
        #pragma unroll
        for (int off = 32; off >= 1; off >>= 1)
            mv = fmaxf(mv, __shfl_xor(mv, off, 64));
        float se = sel ? expf(val - mv) : 0.f;
        #pragma unroll
        for (int off = 32; off >= 1; off >>= 1)
            se += __shfl_xor(se, off, 64);
        float vt = __shfl(val, tgt, 64);        // weighted value at target
        if (lane == 0)
            *gold_out = (m > 0.f) ? (vt - mv - logf(se)) : 0.f;
    }
}

__global__ __launch_bounds__(256) void fused_kernel(
    const float* __restrict__ unaries,
    const float* __restrict__ behaviors,
    const float* __restrict__ interactions,
    const float* __restrict__ wpu,
    const float* __restrict__ wpb,
    const void* masks, const void* bmask, const void* imask,
    const int* __restrict__ edges, const void* binmask,
    const int* __restrict__ targets,
    int* __restrict__ counter,
    float* __restrict__ node_gold,
    float* __restrict__ edge_gold,
    float* __restrict__ out)
{
    int be = blockIdx.x;            // be = b*E + e
    int b = be >> 9;                // /EE
    int tid = threadIdx.x;
    int wid = tid >> 6, lane = tid & 63;

    // --- detect bool storage width (uint8 / int32 / f32); uniform per wave ---
    unsigned int wrd = ((const unsigned int*)bmask)[lane & 31];
    bool anyF = __any(wrd == 0x3F800000u);
    bool anyG = __any(wrd > 1u);
    int flag = anyF ? 2 : (anyG ? 1 : 0);

    __shared__ int beam1[KK], beam2[KK];
    __shared__ float sred[4];
    __shared__ int s_last;

    int n1 = edges[be * 2 + 0];
    int n2 = edges[be * 2 + 1];

    // --- phase 1: per-wave beam computation (+ node gold on wave 2) ---------
    if (wid == 0)
        node_beam(b * NN + n1, lane, flag, unaries, behaviors, masks, targets,
                  wpu, bmask, beam1, nullptr);
    else if (wid == 1)
        node_beam(b * NN + n2, lane, flag, unaries, behaviors, masks, targets,
                  wpu, bmask, beam2, nullptr);
    else if (wid == 2 && be < NNODE)
        node_beam(be, lane, flag, unaries, behaviors, masks, targets,
                  wpu, bmask, nullptr, &node_gold[be]);
    __syncthreads();

    // --- phase 2: K*K beam-pair gather + on-the-fly binary coefficient ------
    int i = tid >> 4, j = tid & 15;
    int s1 = beam1[i], s2 = beam2[j];
    int p = s1 * SS + s2;

    size_t base = (((size_t)(b * NN + n1) * NN + n2) * (SS * SS) + p) * AI;
    float xv[8];
    *(float4*)(xv)     = *(const float4*)(interactions + base);
    *(float4*)(xv + 4) = *(const float4*)(interactions + base + 4);

    float cnt = 0.f, raw = 0.f;
    #pragma unroll
    for (int a = 0; a < AI; ++a) {
        bool mm = read_mask(imask, p * AI + a, flag);
        cnt += mm ? 1.f : 0.f;
        raw += mm ? xv[a] : 0.f;
    }
    if (cnt == 0.f) cnt = 1.f;
    float phi = wpb[p] * (raw / cnt);           // bin_phis[i][j]

    // block logsumexp over 256 values
    float v = phi;
    #pragma unroll
    for (int off = 32; off >= 1; off >>= 1)
        v = fmaxf(v, __shfl_xor(v, off, 64));
    if (lane == 0) sred[wid] = v;
    __syncthreads();
    float mx = fmaxf(fmaxf(sred[0], sred[1]), fmaxf(sred[2], sred[3]));
    __syncthreads();
    float e = expf(phi - mx);
    #pragma unroll
    for (int off = 32; off >= 1; off >>= 1)
        e += __shfl_xor(e, off, 64);
    if (lane == 0) sred[wid] = e;
    __syncthreads();
    if (tid == 0) {
        float s = sred[0] + sred[1] + sred[2] + sred[3];
        float gold = phi - mx - logf(s);        // thread 0 holds phi[0][0]
        bool bm = read_mask(binmask, be, flag);
        edge_gold[be] = bm ? gold : 0.f;
    }

    // --- arrival counter; last block reduces everything ---------------------
    __threadfence();
    if (tid == 0)
        s_last = (atomicAdd(counter, 1) == NBLK - 1) ? 1 : 0;
    __syncthreads();
    if (s_last) {
        __threadfence();
        int bb = wid;                           // wave w handles batch b=w
        float sum = 0.f, cm = 0.f;
        if (lane < NN) {
            sum += node_gold[bb * NN + lane];
            cm += read_mask(masks, bb * NN + lane, flag) ? 1.f : 0.f;
        }
        for (int ee = lane; ee < EE; ee += 64)
            sum += edge_gold[bb * EE + ee];
        #pragma unroll
        for (int off = 32; off >= 1; off >>= 1) {
            sum += __shfl_xor(sum, off, 64);
            cm  += __shfl_xor(cm, off, 64);
        }
        __syncthreads();                        // sred reuse
        if (lane == 0) sred[bb] = sum / cm;
        __syncthreads();
        if (tid == 0)
            out[0] = -(sred[0] + sred[1] + sred[2] + sred[3]) * (1.f / BB);
    }
}

extern "C" void kernel_launch(void* const* d_in, const int* in_sizes, int n_in,
                              void* d_out, int out_size, void* d_ws, size_t ws_size,
                              hipStream_t stream) {
    const float* unaries      = (const float*)d_in[0];
    const float* behaviors    = (const float*)d_in[1];
    const float* interactions = (const float*)d_in[2];
    const float* wpu          = (const float*)d_in[3];
    const float* wpb          = (const float*)d_in[4];
    const void*  masks        = d_in[5];
    const void*  bmask        = d_in[6];
    const void*  imask        = d_in[7];
    const int*   edges        = (const int*)d_in[8];
    const void*  binmask      = d_in[9];
    const int*   targets      = (const int*)d_in[10];
    float* out = (float*)d_out;

    char* ws = (char*)d_ws;
    int*   counter   = (int*)(ws + WS_CNT);
    float* node_gold = (float*)(ws + WS_NG);
    float* edge_gold = (float*)(ws + WS_EG);

    hipMemsetAsync(counter, 0, sizeof(int), stream);
    fused_kernel<<<NBLK, 256, 0, stream>>>(unaries, behaviors, interactions,
                                           wpu, wpb, masks, bmask, imask,
                                           edges, binmask, targets,
                                           counter, node_gold, edge_gold, out);
}

// Round 3
// 21.636 us; speedup vs baseline: 8.5083x; 8.5083x over previous
//
#include <hip/hip_runtime.h>
#include <hip/hip_bf16.h>
#include <math.h>

// Problem constants (fixed by setup_inputs)
#define BB 4
#define NN 48
#define SS 32
#define AA 16
#define AI 8
#define EE 512
#define KK 16
#define NNODE (BB * NN)  // 192
#define NEDGE (BB * EE)  // 2048

// ws layout (byte offsets)
#define WS_CBIN  0         // S*S*AI floats = 32 KB
#define WS_BEAM  32768     // NNODE*KK ints = 12 KB
#define WS_NG    45056     // NNODE floats
#define WS_EG    46080     // NEDGE floats
// total < 56 KB

__device__ __forceinline__ bool read_mask(const void* p, int idx, int flag) {
    if (flag == 1) return ((const unsigned char*)p)[idx] != 0;
    if (flag == 2) return ((const float*)p)[idx] != 0.0f;
    return ((const int*)p)[idx] != 0;
}

// Detect bool storage width (uint8 / int32 / f32) from bmask's first 128 bytes.
// bernoulli(0.5) data makes this unambiguous w.h.p. Uniform per wave.
__device__ __forceinline__ int detect_flag(const void* bmask, int lane) {
    unsigned int wrd = ((const unsigned int*)bmask)[lane & 31];
    bool anyF = __any(wrd == 0x3F800000u);
    bool anyG = __any(wrd > 1u);
    return anyF ? 2 : (anyG ? 1 : 0);
}

// ---------------- Kernel 1: node beams + unary gold, and cbin table ----------
// blocks 0..47   : 4 waves x 1 node each (node = blk*4 + wid)
// blocks 48..79  : cbin[(s1*S+s2)*AI+a] = imask ? wpb[s1,s2]/icnt[s1,s2] : 0
__global__ __launch_bounds__(256) void node_kernel(
    const float* __restrict__ unaries,
    const float* __restrict__ behaviors,
    const float* __restrict__ wpu,
    const float* __restrict__ wpb,
    const void* masks, const void* bmask, const void* imask,
    const int* __restrict__ targets,
    float* __restrict__ cbin,
    int* __restrict__ beam,
    float* __restrict__ node_gold)
{
    int tid = threadIdx.x;
    int wid = tid >> 6, lane = tid & 63;
    int flag = detect_flag(bmask, lane);

    if (blockIdx.x < 48) {
        int node = blockIdx.x * 4 + wid;        // < 192
        float m = read_mask(masks, node, flag) ? 1.f : 0.f;
        int tgt = targets[node];

        float val = -INFINITY, key = -INFINITY;
        if (lane < SS) {
            int s = lane;
            float u = unaries[node * SS + s];
            const float* bp = behaviors + ((size_t)node * SS + s) * AA;
            float cnt = 0.f, raw = 0.f;
            #pragma unroll
            for (int a = 0; a < AA; ++a) {
                bool mm = read_mask(bmask, s * AA + a, flag);
                cnt += mm ? 1.f : 0.f;
                raw += mm ? bp[a] : 0.f;
            }
            if (cnt == 0.f) cnt = 1.f;
            val = m * (u + wpu[s] * (raw / cnt));   // weighted_unaries
            key = (s == tgt) ? INFINITY : val;      // target -> +inf
        }

        // rank = #states with strictly greater key, ties by lower index
        int rank = 0;
        #pragma unroll
        for (int t = 0; t < SS; ++t) {
            float kt = __shfl(key, t, 64);
            rank += (kt > key) || (kt == key && t < lane);
        }
        bool sel = (lane < SS) && (rank < KK);
        if (sel) beam[node * KK + rank] = lane;

        // log-softmax over the 16 selected values; gold = val[target]
        float mv = sel ? val : -INFINITY;
        #pragma unroll
        for (int off = 32; off >= 1; off >>= 1)
            mv = fmaxf(mv, __shfl_xor(mv, off, 64));
        float se = sel ? expf(val - mv) : 0.f;
        #pragma unroll
        for (int off = 32; off >= 1; off >>= 1)
            se += __shfl_xor(se, off, 64);
        float vt = __shfl(val, tgt, 64);
        if (lane == 0)
            node_gold[node] = (m > 0.f) ? (vt - mv - logf(se)) : 0.f;
    } else {
        int idx = (blockIdx.x - 48) * 256 + tid;    // [0, 8192)
        int p = idx >> 3;                           // (s1*S+s2)
        float cnt = 0.f;
        #pragma unroll
        for (int a = 0; a < AI; ++a)
            cnt += read_mask(imask, p * AI + a, flag) ? 1.f : 0.f;
        if (cnt == 0.f) cnt = 1.f;
        bool mm = read_mask(imask, idx, flag);
        cbin[idx] = mm ? (wpb[p] / cnt) : 0.f;
    }
}

// ---------------- Kernel 2: per-edge K*K beam-pair gather + logsumexp --------
__global__ __launch_bounds__(256) void edge_kernel(
    const float* __restrict__ interactions,
    const int* __restrict__ edges,
    const void* binmask, const void* bmask,
    const float* __restrict__ cbin,
    const int* __restrict__ beam,
    float* __restrict__ edge_gold)
{
    int be = blockIdx.x;            // be = b*E + e
    int b = be >> 9;                // /EE
    int tid = threadIdx.x;
    int wid = tid >> 6, lane = tid & 63;

    int n1 = edges[be * 2 + 0];
    int n2 = edges[be * 2 + 1];

    int i = tid >> 4, j = tid & 15;
    int s1 = beam[(b * NN + n1) * KK + i];
    int s2 = beam[(b * NN + n2) * KK + j];
    int p = s1 * SS + s2;

    size_t base = (((size_t)(b * NN + n1) * NN + n2) * (SS * SS) + p) * AI;
    float4 x0 = *(const float4*)(interactions + base);
    float4 x1 = *(const float4*)(interactions + base + 4);
    float4 c0 = *(const float4*)(cbin + p * AI);
    float4 c1 = *(const float4*)(cbin + p * AI + 4);
    float phi = x0.x * c0.x + x0.y * c0.y + x0.z * c0.z + x0.w * c0.w
              + x1.x * c1.x + x1.y * c1.y + x1.z * c1.z + x1.w * c1.w;

    __shared__ float sred[4];
    float v = phi;
    #pragma unroll
    for (int off = 32; off >= 1; off >>= 1)
        v = fmaxf(v, __shfl_xor(v, off, 64));
    if (lane == 0) sred[wid] = v;
    __syncthreads();
    float mx = fmaxf(fmaxf(sred[0], sred[1]), fmaxf(sred[2], sred[3]));
    __syncthreads();
    float e = expf(phi - mx);
    #pragma unroll
    for (int off = 32; off >= 1; off >>= 1)
        e += __shfl_xor(e, off, 64);
    if (lane == 0) sred[wid] = e;
    __syncthreads();
    if (tid == 0) {
        int flag = detect_flag(bmask, lane);
        float s = sred[0] + sred[1] + sred[2] + sred[3];
        float gold = phi - mx - logf(s);        // thread 0 holds phi[0][0]
        bool bm = read_mask(binmask, be, flag);
        edge_gold[be] = bm ? gold : 0.f;
    }
}

// ---------------- Kernel 3: final reduction -> nll ---------------------------
__global__ __launch_bounds__(256) void final_kernel(
    const void* masks, const void* bmask,
    const float* __restrict__ node_gold,
    const float* __restrict__ edge_gold,
    float* __restrict__ out)
{
    int tid = threadIdx.x;          // 4 waves, wave w = batch b
    int b = tid >> 6;
    int lane = tid & 63;
    int flag = detect_flag(bmask, lane);

    float sum = 0.f, cnt = 0.f;
    if (lane < NN) {
        sum += node_gold[b * NN + lane];
        cnt += read_mask(masks, b * NN + lane, flag) ? 1.f : 0.f;
    }
    for (int e = lane; e < EE; e += 64)
        sum += edge_gold[b * EE + e];

    #pragma unroll
    for (int off = 32; off >= 1; off >>= 1) {
        sum += __shfl_xor(sum, off, 64);
        cnt += __shfl_xor(cnt, off, 64);
    }
    __shared__ float sp[4];
    if (lane == 0) sp[b] = sum / cnt;
    __syncthreads();
    if (tid == 0)
        out[0] = -(sp[0] + sp[1] + sp[2] + sp[3]) * (1.f / BB);
}

extern "C" void kernel_launch(void* const* d_in, const int* in_sizes, int n_in,
                              void* d_out, int out_size, void* d_ws, size_t ws_size,
                              hipStream_t stream) {
    const float* unaries      = (const float*)d_in[0];
    const float* behaviors    = (const float*)d_in[1];
    const float* interactions = (const float*)d_in[2];
    const float* wpu          = (const float*)d_in[3];
    const float* wpb          = (const float*)d_in[4];
    const void*  masks        = d_in[5];
    const void*  bmask        = d_in[6];
    const void*  imask        = d_in[7];
    const int*   edges        = (const int*)d_in[8];
    const void*  binmask      = d_in[9];
    const int*   targets      = (const int*)d_in[10];
    float* out = (float*)d_out;

    char* ws = (char*)d_ws;
    float* cbin      = (float*)(ws + WS_CBIN);
    int*   beamp     = (int*)(ws + WS_BEAM);
    float* node_gold = (float*)(ws + WS_NG);
    float* edge_gold = (float*)(ws + WS_EG);

    node_kernel<<<80, 256, 0, stream>>>(unaries, behaviors, wpu, wpb,
                                        masks, bmask, imask, targets,
                                        cbin, beamp, node_gold);
    edge_kernel<<<NEDGE, 256, 0, stream>>>(interactions, edges, binmask, bmask,
                                           cbin, beamp, edge_gold);
    final_kernel<<<1, 256, 0, stream>>>(masks, bmask, node_gold, edge_gold, out);
}